// Round 2
// baseline (384.740 us; speedup 1.0000x reference)
//
#include <hip/hip_runtime.h>

// Problem constants (BS,H,W,C,K = 8,48,48,8,20)
#define BSZ   8
#define HWDIM 2304            // H*W = 48*48
#define NPIX  (BSZ * HWDIM)   // 18432 target pixels
#define NCH   8               // label channels C
#define TOPK  20
#define CAP   96              // candidate cap: mean 52.4, sigma 7.16 -> 6.1 sigma, never overflows
#define TAU   2.0f            // filter threshold (data ~ N(0,1): E[count>2.0] = 52.4)
#define NCHUNK 32
#define CHUNK  (HWDIM / NCHUNK)   // 72 source rows per chunk

// monotone float->uint key: larger float => larger uint (bit-exact invertible)
__device__ __forceinline__ unsigned int fkey(float v) {
    unsigned int u = __float_as_uint(v);
    return (u & 0x80000000u) ? ~u : (u | 0x80000000u);
}
__device__ __forceinline__ float fkey_inv(unsigned int k) {
    unsigned int u = (k & 0x80000000u) ? (k ^ 0x80000000u) : ~k;
    return __uint_as_float(u);
}
// full sort key: value-desc, then index-asc (matches jax.lax.top_k tie-break)
__device__ __forceinline__ unsigned long long mkkey(float v, unsigned int s) {
    return ((unsigned long long)fkey(v) << 32) | (0xFFFFFFFFu - s);
}

// ---------------- K0: transpose labels [b][c][hw] -> [b][hw][c] ----------------
__global__ __launch_bounds__(256) void k0_transpose(const float* __restrict__ lbl,
                                                    float* __restrict__ lblT) {
    int pix = blockIdx.x * 256 + threadIdx.x;          // grid covers NPIX exactly
    int b = pix / HWDIM, p = pix - b * HWDIM;
    const float* src = lbl + (size_t)b * NCH * HWDIM + p;
    float4 lo, hi;
    lo.x = src[0 * HWDIM]; lo.y = src[1 * HWDIM]; lo.z = src[2 * HWDIM]; lo.w = src[3 * HWDIM];
    hi.x = src[4 * HWDIM]; hi.y = src[5 * HWDIM]; hi.z = src[6 * HWDIM]; hi.w = src[7 * HWDIM];
    float4* dst = (float4*)(lblT + (size_t)pix * NCH);
    dst[0] = lo; dst[1] = hi;
}

// ---------------- K1: streaming threshold filter (memory-bound pass) ----------------
// Lanes span consecutive pixels; float2 loads = 8B/lane, fully coalesced.
__global__ __launch_bounds__(256) void k1_filter(const float* __restrict__ corr,
                                                 unsigned int* __restrict__ cnt,
                                                 unsigned long long* __restrict__ cand) {
    const int PIXTILES = NPIX / 512;                   // 36 (each tile = 512 pixels)
    int pixTile = blockIdx.x % PIXTILES;
    int chunk   = blockIdx.x / PIXTILES;
    int pix0 = pixTile * 512 + threadIdx.x * 2;        // this thread's pixel pair
    int b = pix0 / HWDIM;
    int p0 = pix0 - b * HWDIM;
    int s0 = chunk * CHUNK;
    const float2* ptr =
        (const float2*)(corr + ((size_t)b * HWDIM + s0) * HWDIM + p0);
#pragma unroll 4
    for (int j = 0; j < CHUNK; ++j) {
        float2 v = ptr[(size_t)j * (HWDIM / 2)];
        unsigned int s = (unsigned int)(s0 + j);
        if (v.x > TAU) {
            unsigned int slot = atomicAdd(&cnt[pix0], 1u);
            if (slot < CAP) cand[(size_t)slot * NPIX + pix0] = mkkey(v.x, s);
        }
        if (v.y > TAU) {
            unsigned int slot = atomicAdd(&cnt[pix0 + 1], 1u);
            if (slot < CAP) cand[(size_t)slot * NPIX + pix0 + 1] = mkkey(v.y, s);
        }
    }
}

// ---------------- K2: exact top-20 select + label gather ----------------
__global__ __launch_bounds__(256) void k2_select(const float* __restrict__ corr,
                                                 const float* __restrict__ lbl,
                                                 const float* __restrict__ lblT,
                                                 const unsigned int* __restrict__ cnt,
                                                 const unsigned long long* __restrict__ cand,
                                                 float* __restrict__ out,
                                                 int use_ws) {
    int pix = blockIdx.x * 256 + threadIdx.x;
    int b = pix / HWDIM, p = pix - b * HWDIM;
    unsigned int n = use_ws ? cnt[pix] : 0u;

    // d[] ascending; d[0] = min of kept set; key 0 = -inf sentinel
    unsigned long long d[TOPK];
#pragma unroll
    for (int i = 0; i < TOPK; ++i) d[i] = 0ull;

    auto push = [&](unsigned long long key) {
        if (key > d[0]) {
            d[0] = key;
#pragma unroll
            for (int j = 0; j < TOPK - 1; ++j) {
                unsigned long long a = d[j], c2 = d[j + 1];
                bool sw = a > c2;
                d[j]     = sw ? c2 : a;
                d[j + 1] = sw ? a : c2;
            }
        }
    };

    if (use_ws && n >= TOPK && n <= CAP) {
        // coalesced: consecutive lanes read consecutive u64s per slot
        for (unsigned int i = 0; i < n; ++i)
            push(cand[(size_t)i * NPIX + pix]);
    } else {
        // exact fallback: full rescan of this pixel's column (rare: ~0.06 px expected)
        const float* ptr = corr + (size_t)b * HWDIM * HWDIM + p;
        for (int s = 0; s < HWDIM; ++s)
            push(mkkey(ptr[(size_t)s * HWDIM], (unsigned int)s));
    }

    float acc[NCH];
#pragma unroll
    for (int c = 0; c < NCH; ++c) acc[c] = 0.0f;

#pragma unroll
    for (int i = 0; i < TOPK; ++i) {
        float v = fkey_inv((unsigned int)(d[i] >> 32));
        unsigned int s = 0xFFFFFFFFu - (unsigned int)d[i];
        if (use_ws) {
            const float4* lp = (const float4*)(lblT + ((size_t)b * HWDIM + s) * NCH);
            float4 lo = lp[0], hi = lp[1];
            acc[0] += v * lo.x; acc[1] += v * lo.y; acc[2] += v * lo.z; acc[3] += v * lo.w;
            acc[4] += v * hi.x; acc[5] += v * hi.y; acc[6] += v * hi.z; acc[7] += v * hi.w;
        } else {
            const float* lb = lbl + (size_t)b * NCH * HWDIM + s;
#pragma unroll
            for (int c = 0; c < NCH; ++c) acc[c] += v * lb[(size_t)c * HWDIM];
        }
    }
#pragma unroll
    for (int c = 0; c < NCH; ++c)
        out[((size_t)b * NCH + c) * HWDIM + p] = acc[c];
}

extern "C" void kernel_launch(void* const* d_in, const int* in_sizes, int n_in,
                              void* d_out, int out_size, void* d_ws, size_t ws_size,
                              hipStream_t stream) {
    const float* corr = (const float*)d_in[0];  // (8, 2304, 48, 48) fp32
    const float* lbl  = (const float*)d_in[1];  // (8, 8, 48, 48) fp32
    float* out = (float*)d_out;                 // (8, 8, 48, 48) fp32

    // ws layout: [cnt: NPIX u32][cand: CAP*NPIX u64][lblT: NPIX*NCH f32]
    const size_t cnt_bytes  = (size_t)NPIX * sizeof(unsigned int);
    const size_t cand_bytes = (size_t)CAP * NPIX * sizeof(unsigned long long);
    const size_t lblT_bytes = (size_t)NPIX * NCH * sizeof(float);
    const size_t needed = cnt_bytes + cand_bytes + lblT_bytes;

    dim3 blk(256);
    if (ws_size >= needed) {
        unsigned int* cnt = (unsigned int*)d_ws;
        unsigned long long* cand = (unsigned long long*)((char*)d_ws + cnt_bytes);
        float* lblT = (float*)((char*)d_ws + cnt_bytes + cand_bytes);

        hipMemsetAsync(cnt, 0, cnt_bytes, stream);
        k0_transpose<<<dim3(NPIX / 256), blk, 0, stream>>>(lbl, lblT);
        k1_filter<<<dim3((NPIX / 512) * NCHUNK), blk, 0, stream>>>(corr, cnt, cand);
        k2_select<<<dim3(NPIX / 256), blk, 0, stream>>>(corr, lbl, lblT, cnt, cand, out, 1);
    } else {
        // workspace too small: fully self-contained exact path (slow but correct)
        k2_select<<<dim3(NPIX / 256), blk, 0, stream>>>(corr, lbl, nullptr, nullptr, nullptr, out, 0);
    }
}

// Round 7
// 377.321 us; speedup vs baseline: 1.0197x; 1.0197x over previous
//
#include <hip/hip_runtime.h>

// Problem constants (BS,H,W,C,K = 8,48,48,8,20)
#define BSZ    8
#define HWDIM  2304               // 48*48
#define NPIX   (BSZ * HWDIM)      // 18432
#define NCH    8
#define TOPK   20
#define NCHUNK 32
#define CHUNK  72                 // HWDIM / NCHUNK
#define CAPC   13                 // per-(pixel,chunk) slot capacity; Poisson(1.64) P(>13)~2e-9
#define TAU    2.0f               // N(0,1): E[#>TAU per pixel] = 52.4
#define QCH    8                  // chunks per quarter (k2a)
#define NQ     4                  // quarters per pixel

// monotone float<->uint key (bit-exact invertible)
__device__ __forceinline__ unsigned int fkey(float v) {
    unsigned int u = __float_as_uint(v);
    return (u & 0x80000000u) ? ~u : (u | 0x80000000u);
}
__device__ __forceinline__ float fkey_inv(unsigned int k) {
    unsigned int u = (k & 0x80000000u) ? (k ^ 0x80000000u) : ~k;
    return __uint_as_float(u);
}
// full order key: value desc, then source-index asc (jax.lax.top_k tie-break)
__device__ __forceinline__ unsigned long long mk64(unsigned int vk, unsigned int s) {
    return ((unsigned long long)vk << 32) | (0xFFFFFFFFu - s);
}

// keep-top-20 set: d[] ascending, d[0]=min. One bubble pass restores order.
#define PUSH(KEY) do { unsigned long long _k = (KEY); if (_k > d[0]) { d[0] = _k;   \
    _Pragma("unroll") for (int _j = 0; _j < TOPK - 1; ++_j) {                        \
        unsigned long long _a = d[_j], _b = d[_j + 1];                               \
        bool _sw = _a > _b; d[_j] = _sw ? _b : _a; d[_j + 1] = _sw ? _a : _b; } } } while (0)

// ---------------- K0: labels [b][c][hw] -> [b][hw][c] ----------------
__global__ __launch_bounds__(256) void k0_transpose(const float* __restrict__ lbl,
                                                    float* __restrict__ lblT) {
    int pix = blockIdx.x * 256 + threadIdx.x;
    int b = pix / HWDIM, p = pix - b * HWDIM;
    const float* src = lbl + (size_t)b * NCH * HWDIM + p;
    float4 lo, hi;
    lo.x = src[0 * HWDIM]; lo.y = src[1 * HWDIM]; lo.z = src[2 * HWDIM]; lo.w = src[3 * HWDIM];
    hi.x = src[4 * HWDIM]; hi.y = src[5 * HWDIM]; hi.z = src[6 * HWDIM]; hi.w = src[7 * HWDIM];
    float4* dst = (float4*)(lblT + (size_t)pix * NCH);
    dst[0] = lo; dst[1] = hi;
}

// ---------------- K1: streaming filter, NO atomics, LDS-staged coalesced flush ----------------
// block = (pixel tile of 512, chunk of 72 source rows); thread owns 2 pixels (float2 loads).
__global__ __launch_bounds__(256) void k1_filter(const float* __restrict__ corr,
                                                 unsigned char* __restrict__ cntc,
                                                 unsigned int* __restrict__ gval,
                                                 unsigned char* __restrict__ gidx) {
    __shared__ unsigned int  lval[CAPC][512];
    __shared__ unsigned char lidx[CAPC][512];
    const int PIXTILES = NPIX / 512;             // 36
    int tile  = blockIdx.x % PIXTILES;
    int chunk = blockIdx.x / PIXTILES;
    int t = threadIdx.x;
    int pix0 = tile * 512 + t * 2;
    int b = pix0 / HWDIM;                        // pair never straddles b (boundaries even)
    int p0 = pix0 - b * HWDIM;
    int s0 = chunk * CHUNK;
    const float2* ptr = (const float2*)(corr + ((size_t)b * HWDIM + s0) * HWDIM + p0);
    int c0 = 0, c1 = 0;
#pragma unroll 4
    for (int j = 0; j < CHUNK; ++j) {
        float2 v = ptr[(size_t)j * (HWDIM / 2)];
        if (v.x > TAU) { if (c0 < CAPC) { lval[c0][2 * t]     = fkey(v.x); lidx[c0][2 * t]     = (unsigned char)j; } c0++; }
        if (v.y > TAU) { if (c1 < CAPC) { lval[c1][2 * t + 1] = fkey(v.y); lidx[c1][2 * t + 1] = (unsigned char)j; } c1++; }
    }
    cntc[(size_t)chunk * NPIX + pix0]     = (unsigned char)c0;   // true count (may exceed CAPC)
    cntc[(size_t)chunk * NPIX + pix0 + 1] = (unsigned char)c1;
    __syncthreads();
    // coalesced flush (unused slots carry garbage; gated by cntc at read time)
#pragma unroll
    for (int slot = 0; slot < CAPC; ++slot) {
        size_t base = ((size_t)chunk * CAPC + slot) * NPIX + (size_t)tile * 512;
        gval[base + t]        = lval[slot][t];
        gval[base + t + 256]  = lval[slot][t + 256];
        gidx[base + t]        = lidx[slot][t];
        gidx[base + t + 256]  = lidx[slot][t + 256];
    }
}

// ---------------- K2a: per-(pixel, quarter of 8 chunks) partial top-20 ----------------
// 288 blocks x 256 threads = 1152 waves (fills all CUs). Wave = 64 pixels, one quarter.
__global__ __launch_bounds__(256) void k2a_part(const float* __restrict__ corr,
                                                const unsigned char* __restrict__ cntc,
                                                const unsigned int* __restrict__ gval,
                                                const unsigned char* __restrict__ gidx,
                                                unsigned long long* __restrict__ part) {
    int t = threadIdx.x;
    int pix = blockIdx.x * 64 + (t & 63);
    int q = t >> 6;
    int b = pix / HWDIM, p = pix - b * HWDIM;
    unsigned long long d[TOPK];
#pragma unroll
    for (int i = 0; i < TOPK; ++i) d[i] = 0ull;

    for (int cc = 0; cc < QCH; ++cc) {
        int chunk = q * QCH + cc;
        unsigned int nc = cntc[(size_t)chunk * NPIX + pix];
        unsigned int vv[CAPC], ii[CAPC];
        // unconditional batch loads -> all CAPC in flight (pipelined)
#pragma unroll
        for (int s2 = 0; s2 < CAPC; ++s2) {
            size_t base = ((size_t)chunk * CAPC + s2) * NPIX + pix;
            vv[s2] = gval[base];
            ii[s2] = gidx[base];
        }
        bool ov = (nc > CAPC);                   // slot overflow: essentially never
#pragma unroll
        for (int s2 = 0; s2 < CAPC; ++s2) {
            if (!ov && s2 < (int)nc)
                PUSH(mk64(vv[s2], (unsigned)(chunk * CHUNK) + ii[s2]));
        }
        if (__builtin_expect(ov, 0)) {           // exact rescan of this chunk only
            const float* cp = corr + ((size_t)b * HWDIM + chunk * CHUNK) * HWDIM + p;
            for (int j2 = 0; j2 < CHUNK; ++j2) {
                float v = cp[(size_t)j2 * HWDIM];
                if (v > TAU) PUSH(mk64(fkey(v), (unsigned)(chunk * CHUNK + j2)));
            }
        }
    }
#pragma unroll
    for (int i = 0; i < TOPK; ++i)
        part[((size_t)q * TOPK + i) * NPIX + pix] = d[i];
}

// ---------------- K2b: merge 4x20 keys -> final top-20 -> label gather ----------------
// 288 blocks x 64 threads: one wave per block, spread across all CUs.
__global__ __launch_bounds__(64) void k2b_merge(const float* __restrict__ corr,
                                                const float* __restrict__ lblT,
                                                const unsigned long long* __restrict__ part,
                                                float* __restrict__ out) {
    int pix = blockIdx.x * 64 + threadIdx.x;
    int b = pix / HWDIM, p = pix - b * HWDIM;
    unsigned long long d[TOPK];
#pragma unroll
    for (int i = 0; i < TOPK; ++i) d[i] = 0ull;
    int ntot = 0;
#pragma unroll
    for (int q = 0; q < NQ; ++q) {
        unsigned long long kk[TOPK];
#pragma unroll
        for (int i = 0; i < TOPK; ++i)
            kk[i] = part[((size_t)(q * TOPK + i)) * NPIX + pix];
#pragma unroll
        for (int i = 0; i < TOPK; ++i)
            if (kk[i] != 0ull) { ntot++; PUSH(kk[i]); }
    }
    if (ntot < TOPK) {                            // <20 candidates above TAU: exact full rescan
#pragma unroll
        for (int i = 0; i < TOPK; ++i) d[i] = 0ull;
        const float* cp = corr + (size_t)b * HWDIM * HWDIM + p;
        for (int s = 0; s < HWDIM; ++s)
            PUSH(mk64(fkey(cp[(size_t)s * HWDIM]), (unsigned)s));
    }
    float acc[NCH];
#pragma unroll
    for (int c = 0; c < NCH; ++c) acc[c] = 0.0f;
#pragma unroll
    for (int i = 0; i < TOPK; ++i) {
        float v = fkey_inv((unsigned int)(d[i] >> 32));
        unsigned int s = 0xFFFFFFFFu - (unsigned int)d[i];
        const float4* lp = (const float4*)(lblT + ((size_t)b * HWDIM + s) * NCH);
        float4 lo = lp[0], hi = lp[1];
        acc[0] += v * lo.x; acc[1] += v * lo.y; acc[2] += v * lo.z; acc[3] += v * lo.w;
        acc[4] += v * hi.x; acc[5] += v * hi.y; acc[6] += v * hi.z; acc[7] += v * hi.w;
    }
#pragma unroll
    for (int c = 0; c < NCH; ++c)
        out[((size_t)b * NCH + c) * HWDIM + p] = acc[c];
}

// ---------------- fallback (ws too small): exact, self-contained ----------------
__global__ __launch_bounds__(64) void k_fallback(const float* __restrict__ corr,
                                                 const float* __restrict__ lbl,
                                                 float* __restrict__ out) {
    int pix = blockIdx.x * 64 + threadIdx.x;
    int b = pix / HWDIM, p = pix - b * HWDIM;
    unsigned long long d[TOPK];
#pragma unroll
    for (int i = 0; i < TOPK; ++i) d[i] = 0ull;
    const float* cp = corr + (size_t)b * HWDIM * HWDIM + p;
    for (int s = 0; s < HWDIM; ++s)
        PUSH(mk64(fkey(cp[(size_t)s * HWDIM]), (unsigned)s));
    float acc[NCH];
#pragma unroll
    for (int c = 0; c < NCH; ++c) acc[c] = 0.0f;
    const float* lb = lbl + (size_t)b * NCH * HWDIM;
#pragma unroll
    for (int i = 0; i < TOPK; ++i) {
        float v = fkey_inv((unsigned int)(d[i] >> 32));
        unsigned int s = 0xFFFFFFFFu - (unsigned int)d[i];
#pragma unroll
        for (int c = 0; c < NCH; ++c) acc[c] += v * lb[(size_t)c * HWDIM + s];
    }
#pragma unroll
    for (int c = 0; c < NCH; ++c)
        out[((size_t)b * NCH + c) * HWDIM + p] = acc[c];
}

extern "C" void kernel_launch(void* const* d_in, const int* in_sizes, int n_in,
                              void* d_out, int out_size, void* d_ws, size_t ws_size,
                              hipStream_t stream) {
    const float* corr = (const float*)d_in[0];  // (8, 2304, 48, 48) fp32
    const float* lbl  = (const float*)d_in[1];  // (8, 8, 48, 48) fp32
    float* out = (float*)d_out;

    // ws layout (256B-aligned sections)
    auto align256 = [](size_t x) { return (x + 255) & ~(size_t)255; };
    size_t off = 0;
    size_t part_off = off; off += align256((size_t)NQ * TOPK * NPIX * 8);        // 11.8 MB u64
    size_t gval_off = off; off += align256((size_t)NCHUNK * CAPC * NPIX * 4);    // 30.7 MB u32
    size_t lblT_off = off; off += align256((size_t)NPIX * NCH * 4);              // 0.59 MB
    size_t cntc_off = off; off += align256((size_t)NCHUNK * NPIX);               // 0.59 MB u8
    size_t gidx_off = off; off += align256((size_t)NCHUNK * CAPC * NPIX);        // 7.7 MB u8
    size_t needed = off;

    if (ws_size >= needed) {
        unsigned long long* part = (unsigned long long*)((char*)d_ws + part_off);
        unsigned int* gval = (unsigned int*)((char*)d_ws + gval_off);
        float* lblT = (float*)((char*)d_ws + lblT_off);
        unsigned char* cntc = (unsigned char*)((char*)d_ws + cntc_off);
        unsigned char* gidx = (unsigned char*)((char*)d_ws + gidx_off);

        k0_transpose<<<dim3(NPIX / 256), dim3(256), 0, stream>>>(lbl, lblT);
        k1_filter<<<dim3((NPIX / 512) * NCHUNK), dim3(256), 0, stream>>>(corr, cntc, gval, gidx);
        k2a_part<<<dim3(NPIX / 64), dim3(256), 0, stream>>>(corr, cntc, gval, gidx, part);
        k2b_merge<<<dim3(NPIX / 64), dim3(64), 0, stream>>>(corr, lblT, part, out);
    } else {
        k_fallback<<<dim3(NPIX / 64), dim3(64), 0, stream>>>(corr, lbl, out);
    }
}

// Round 9
// 343.557 us; speedup vs baseline: 1.1199x; 1.0983x over previous
//
#include <hip/hip_runtime.h>

// Problem constants (BS,H,W,C,K = 8,48,48,8,20)
#define BSZ    8
#define HWDIM  2304               // 48*48
#define NPIX   (BSZ * HWDIM)      // 18432
#define NCH    8
#define TOPK   20
#define NCHUNK 32
#define CHUNK  72                 // HWDIM / NCHUNK
#define CAPC   13                 // slots; only counts <= CAPC-1 are trusted (branchless writes)
#define TAU    2.0f               // N(0,1): E[#>TAU per pixel] = 52.4
#define QCH    8                  // chunks per quarter
#define NQ     4                  // quarters per pixel
#define NBATCH 6
#define BLEN   12                 // CHUNK = NBATCH*BLEN burst loads

// monotone float<->uint key (bit-exact invertible), branchless
__device__ __forceinline__ unsigned int fkey(float v) {
    unsigned int u = __float_as_uint(v);
    return u ^ (unsigned int)(((int)u >> 31) | 0x80000000);
}
__device__ __forceinline__ float fkey_inv(unsigned int k) {
    unsigned int u = (k & 0x80000000u) ? (k ^ 0x80000000u) : ~k;
    return __uint_as_float(u);
}
// full order key: value desc, then source-index asc (jax.lax.top_k tie-break)
__device__ __forceinline__ unsigned long long mk64(unsigned int vk, unsigned int s) {
    return ((unsigned long long)vk << 32) | (0xFFFFFFFFu - s);
}

// keep-top-20 set: d[] ascending, d[0]=min. One bubble pass restores order.
#define PUSH(KEY) do { unsigned long long _k = (KEY); if (_k > d[0]) { d[0] = _k;   \
    _Pragma("unroll") for (int _j = 0; _j < TOPK - 1; ++_j) {                        \
        unsigned long long _a = d[_j], _b = d[_j + 1];                               \
        bool _sw = _a > _b; d[_j] = _sw ? _b : _a; d[_j + 1] = _sw ? _a : _b; } } } while (0)

// ---------------- K0: labels [b][c][hw] -> [b][hw][c] ----------------
__global__ __launch_bounds__(256) void k0_transpose(const float* __restrict__ lbl,
                                                    float* __restrict__ lblT) {
    int pix = blockIdx.x * 256 + threadIdx.x;
    int b = pix / HWDIM, p = pix - b * HWDIM;
    const float* src = lbl + (size_t)b * NCH * HWDIM + p;
    float4 lo, hi;
    lo.x = src[0 * HWDIM]; lo.y = src[1 * HWDIM]; lo.z = src[2 * HWDIM]; lo.w = src[3 * HWDIM];
    hi.x = src[4 * HWDIM]; hi.y = src[5 * HWDIM]; hi.z = src[6 * HWDIM]; hi.w = src[7 * HWDIM];
    float4* dst = (float4*)(lblT + (size_t)pix * NCH);
    dst[0] = lo; dst[1] = hi;
}

// ---------------- K1: burst-load + BRANCHLESS filter ----------------
// block = (512-px tile, 72-row chunk); thread owns 2 pixels (float2).
// 12 unconditional loads per batch (6 KB/wave in flight), then branchless
// LDS push: ALWAYS write to slot min(c,CAPC-1), advance c only on hit.
// Slots 0..min(c,CAPC-1)-1 are immutable once written; slot >= final c (or
// slot CAPC-1 when c >= CAPC) may hold garbage -> reader trusts c <= CAPC-1 only.
__global__ __launch_bounds__(256) void k1_filter(const float* __restrict__ corr,
                                                 unsigned char* __restrict__ cntc,
                                                 unsigned int* __restrict__ gval,
                                                 unsigned char* __restrict__ gidx) {
    __shared__ unsigned int  lval[CAPC][512];
    __shared__ unsigned char lidx[CAPC][512];
    const int PIXTILES = NPIX / 512;             // 36
    int tile  = blockIdx.x % PIXTILES;
    int chunk = blockIdx.x / PIXTILES;
    int t = threadIdx.x;
    int pix0 = tile * 512 + t * 2;
    int b = pix0 / HWDIM;
    int p0 = pix0 - b * HWDIM;
    int s0 = chunk * CHUNK;
    const float2* ptr = (const float2*)(corr + ((size_t)b * HWDIM + s0) * HWDIM + p0);
    int c0 = 0, c1 = 0;
    for (int batch = 0; batch < NBATCH; ++batch) {
        float2 r[BLEN];
#pragma unroll
        for (int u = 0; u < BLEN; ++u)
            r[u] = ptr[(size_t)(batch * BLEN + u) * (HWDIM / 2)];
#pragma unroll
        for (int u = 0; u < BLEN; ++u) {
            int j = batch * BLEN + u;
            int w0 = c0 < CAPC - 1 ? c0 : CAPC - 1;   // branchless clamp
            lval[w0][2 * t] = fkey(r[u].x);
            lidx[w0][2 * t] = (unsigned char)j;
            c0 += (r[u].x > TAU) ? 1 : 0;
            int w1 = c1 < CAPC - 1 ? c1 : CAPC - 1;
            lval[w1][2 * t + 1] = fkey(r[u].y);
            lidx[w1][2 * t + 1] = (unsigned char)j;
            c1 += (r[u].y > TAU) ? 1 : 0;
        }
    }
    cntc[(size_t)chunk * NPIX + pix0]     = (unsigned char)c0;   // true count
    cntc[(size_t)chunk * NPIX + pix0 + 1] = (unsigned char)c1;
    __syncthreads();
    // coalesced flush (garbage slots gated by cntc at read time)
#pragma unroll
    for (int slot = 0; slot < CAPC; ++slot) {
        size_t base = ((size_t)chunk * CAPC + slot) * NPIX + (size_t)tile * 512;
        gval[base + t]        = lval[slot][t];
        gval[base + t + 256]  = lval[slot][t + 256];
        gidx[base + t]        = lidx[slot][t];
        gidx[base + t + 256]  = lidx[slot][t + 256];
    }
}

// ---------------- K2 fused: quarter partials (phase A) + merge/gather (phase B) ----------------
// 288 blocks x 256 threads. Phase A: thread = (pixel, quarter) -> top-20 into LDS.
// Phase B: threads 0..63 merge 4x20, exact fallbacks, gather labels, store.
__global__ __launch_bounds__(256) void k2_fused(const float* __restrict__ corr,
                                                const float* __restrict__ lblT,
                                                const unsigned char* __restrict__ cntc,
                                                const unsigned int* __restrict__ gval,
                                                const unsigned char* __restrict__ gidx,
                                                float* __restrict__ out) {
    __shared__ unsigned long long sd[TOPK][256];   // [key][thread] -> lane-stride 8B, 2-way free
    int t = threadIdx.x;
    int px64 = blockIdx.x * 64;
    {
        int pix = px64 + (t & 63);
        int q = t >> 6;
        int b = pix / HWDIM, p = pix - b * HWDIM;
        unsigned long long d[TOPK];
#pragma unroll
        for (int i = 0; i < TOPK; ++i) d[i] = 0ull;
        for (int cc = 0; cc < QCH; ++cc) {
            int chunk = q * QCH + cc;
            unsigned int nc = cntc[(size_t)chunk * NPIX + pix];
            unsigned int vv[CAPC], ii[CAPC];
#pragma unroll
            for (int s2 = 0; s2 < CAPC; ++s2) {          // unconditional batch: pipelined
                size_t base = ((size_t)chunk * CAPC + s2) * NPIX + pix;
                vv[s2] = gval[base];
                ii[s2] = gidx[base];
            }
            // CORRECTNESS: branchless k1 can corrupt slot CAPC-1 once count
            // reaches CAPC, so only counts <= CAPC-1 are trusted.
            bool ov = (nc >= CAPC);
#pragma unroll
            for (int s2 = 0; s2 < CAPC; ++s2)
                if (!ov && s2 < (int)nc)
                    PUSH(mk64(vv[s2], (unsigned)(chunk * CHUNK) + ii[s2]));
            if (__builtin_expect(ov, 0)) {               // exact per-chunk rescan (~0.1 lanes/run)
                const float* cp = corr + ((size_t)b * HWDIM + chunk * CHUNK) * HWDIM + p;
                for (int j2 = 0; j2 < CHUNK; ++j2) {
                    float v = cp[(size_t)j2 * HWDIM];
                    if (v > TAU) PUSH(mk64(fkey(v), (unsigned)(chunk * CHUNK + j2)));
                }
            }
        }
#pragma unroll
        for (int i = 0; i < TOPK; ++i) sd[i][t] = d[i];
    }
    __syncthreads();
    if (t < 64) {
        int pix = px64 + t;
        int b = pix / HWDIM, p = pix - b * HWDIM;
        unsigned long long d[TOPK];
#pragma unroll
        for (int i = 0; i < TOPK; ++i) d[i] = 0ull;
        int ntot = 0;
#pragma unroll
        for (int q = 0; q < NQ; ++q)
#pragma unroll
            for (int i = 0; i < TOPK; ++i) {
                unsigned long long k = sd[i][q * 64 + t];
                if (k != 0ull) { ntot++; PUSH(k); }
            }
        if (__builtin_expect(ntot < TOPK, 0)) {          // <20 above TAU: exact full rescan
#pragma unroll
            for (int i = 0; i < TOPK; ++i) d[i] = 0ull;
            const float* cp = corr + (size_t)b * HWDIM * HWDIM + p;
            for (int s = 0; s < HWDIM; ++s)
                PUSH(mk64(fkey(cp[(size_t)s * HWDIM]), (unsigned)s));
        }
        float acc[NCH];
#pragma unroll
        for (int c = 0; c < NCH; ++c) acc[c] = 0.0f;
#pragma unroll
        for (int i = 0; i < TOPK; ++i) {
            float v = fkey_inv((unsigned int)(d[i] >> 32));
            unsigned int s = 0xFFFFFFFFu - (unsigned int)d[i];
            const float4* lp = (const float4*)(lblT + ((size_t)b * HWDIM + s) * NCH);
            float4 lo = lp[0], hi = lp[1];
            acc[0] += v * lo.x; acc[1] += v * lo.y; acc[2] += v * lo.z; acc[3] += v * lo.w;
            acc[4] += v * hi.x; acc[5] += v * hi.y; acc[6] += v * hi.z; acc[7] += v * hi.w;
        }
#pragma unroll
        for (int c = 0; c < NCH; ++c)
            out[((size_t)b * NCH + c) * HWDIM + p] = acc[c];
    }
}

// ---------------- fallback (ws too small): exact, self-contained ----------------
__global__ __launch_bounds__(64) void k_fallback(const float* __restrict__ corr,
                                                 const float* __restrict__ lbl,
                                                 float* __restrict__ out) {
    int pix = blockIdx.x * 64 + threadIdx.x;
    int b = pix / HWDIM, p = pix - b * HWDIM;
    unsigned long long d[TOPK];
#pragma unroll
    for (int i = 0; i < TOPK; ++i) d[i] = 0ull;
    const float* cp = corr + (size_t)b * HWDIM * HWDIM + p;
    for (int s = 0; s < HWDIM; ++s)
        PUSH(mk64(fkey(cp[(size_t)s * HWDIM]), (unsigned)s));
    float acc[NCH];
#pragma unroll
    for (int c = 0; c < NCH; ++c) acc[c] = 0.0f;
    const float* lb = lbl + (size_t)b * NCH * HWDIM;
#pragma unroll
    for (int i = 0; i < TOPK; ++i) {
        float v = fkey_inv((unsigned int)(d[i] >> 32));
        unsigned int s = 0xFFFFFFFFu - (unsigned int)d[i];
#pragma unroll
        for (int c = 0; c < NCH; ++c) acc[c] += v * lb[(size_t)c * HWDIM + s];
    }
#pragma unroll
    for (int c = 0; c < NCH; ++c)
        out[((size_t)b * NCH + c) * HWDIM + p] = acc[c];
}

extern "C" void kernel_launch(void* const* d_in, const int* in_sizes, int n_in,
                              void* d_out, int out_size, void* d_ws, size_t ws_size,
                              hipStream_t stream) {
    const float* corr = (const float*)d_in[0];  // (8, 2304, 48, 48) fp32
    const float* lbl  = (const float*)d_in[1];  // (8, 8, 48, 48) fp32
    float* out = (float*)d_out;

    // ws layout (256B-aligned): [gval u32][lblT f32][cntc u8][gidx u8]  (~39.6 MB)
    auto align256 = [](size_t x) { return (x + 255) & ~(size_t)255; };
    size_t off = 0;
    size_t gval_off = off; off += align256((size_t)NCHUNK * CAPC * NPIX * 4);    // 30.7 MB
    size_t lblT_off = off; off += align256((size_t)NPIX * NCH * 4);              // 0.59 MB
    size_t cntc_off = off; off += align256((size_t)NCHUNK * NPIX);               // 0.59 MB
    size_t gidx_off = off; off += align256((size_t)NCHUNK * CAPC * NPIX);        // 7.7 MB
    size_t needed = off;

    if (ws_size >= needed) {
        unsigned int* gval = (unsigned int*)((char*)d_ws + gval_off);
        float* lblT = (float*)((char*)d_ws + lblT_off);
        unsigned char* cntc = (unsigned char*)((char*)d_ws + cntc_off);
        unsigned char* gidx = (unsigned char*)((char*)d_ws + gidx_off);

        k0_transpose<<<dim3(NPIX / 256), dim3(256), 0, stream>>>(lbl, lblT);
        k1_filter<<<dim3((NPIX / 512) * NCHUNK), dim3(256), 0, stream>>>(corr, cntc, gval, gidx);
        k2_fused<<<dim3(NPIX / 64), dim3(256), 0, stream>>>(corr, lblT, cntc, gval, gidx, out);
    } else {
        k_fallback<<<dim3(NPIX / 64), dim3(64), 0, stream>>>(corr, lbl, out);
    }
}

// Round 11
// 300.890 us; speedup vs baseline: 1.2787x; 1.1418x over previous
//
#include <hip/hip_runtime.h>

// Problem constants (BS,H,W,C,K = 8,48,48,8,20)
#define BSZ    8
#define HWDIM  2304               // 48*48
#define NPIX   (BSZ * HWDIM)      // 18432
#define NCH    8
#define TOPK   20
#define NCHUNK 32
#define CHUNK  72                 // HWDIM / NCHUNK
#define CAPC   12                 // branchless slots; trusted cnt <= 11
#define REC    16                 // padded record slots (64B val / 16B idx)
#define TAU    2.0f               // N(0,1): E[#>TAU per pixel] = 52.4
#define NBATCH 6
#define BLEN   12                 // CHUNK = NBATCH*BLEN burst loads
#define LVS    17                 // lval LDS row stride (words)
#define LIS    36                 // lidx LDS row stride (bytes, u32-aligned)

// monotone float<->uint key (bit-exact invertible)
__device__ __forceinline__ unsigned int fkey(float v) {
    unsigned int u = __float_as_uint(v);
    return u ^ (unsigned int)(((int)u >> 31) | 0x80000000);
}
__device__ __forceinline__ float fkey_inv(unsigned int k) {
    unsigned int u = (k & 0x80000000u) ? (k ^ 0x80000000u) : ~k;
    return __uint_as_float(u);
}
// order key: value desc, then source-index asc (jax.lax.top_k tie-break)
__device__ __forceinline__ unsigned long long mk64(unsigned int vk, unsigned int s) {
    return ((unsigned long long)vk << 32) | (0xFFFFFFFFu - s);
}

// keep-top-20 (used only by ws-too-small fallback kernel)
#define PUSH(KEY) do { unsigned long long _k = (KEY); if (_k > d[0]) { d[0] = _k;   \
    _Pragma("unroll") for (int _j = 0; _j < TOPK - 1; ++_j) {                        \
        unsigned long long _a = d[_j], _b = d[_j + 1];                               \
        bool _sw = _a > _b; d[_j] = _sw ? _b : _a; d[_j + 1] = _sw ? _a : _b; } } } while (0)

// ---------------- K0: labels [b][c][hw] -> [b][hw][c] ----------------
__global__ __launch_bounds__(256) void k0_transpose(const float* __restrict__ lbl,
                                                    float* __restrict__ lblT) {
    int pix = blockIdx.x * 256 + threadIdx.x;
    int b = pix / HWDIM, p = pix - b * HWDIM;
    const float* src = lbl + (size_t)b * NCH * HWDIM + p;
    float4 lo, hi;
    lo.x = src[0 * HWDIM]; lo.y = src[1 * HWDIM]; lo.z = src[2 * HWDIM]; lo.w = src[3 * HWDIM];
    hi.x = src[4 * HWDIM]; hi.y = src[5 * HWDIM]; hi.z = src[6 * HWDIM]; hi.w = src[7 * HWDIM];
    float4* dst = (float4*)(lblT + (size_t)pix * NCH);
    dst[0] = lo; dst[1] = hi;
}

// ---------------- K1: burst-load + branchless filter -> per-pixel padded records ----------------
// gval[pix][chunk*16 + slot] u32, gidx[pix][chunk*16 + slot] u8 (full-line records),
// cntc[chunk][pix] u8. Trusted only when cnt <= CAPC-1 = 11 (branchless slot-11 corruption).
__global__ __launch_bounds__(256) void k1_filter(const float* __restrict__ corr,
                                                 unsigned char* __restrict__ cntc,
                                                 unsigned int* __restrict__ gval,
                                                 unsigned char* __restrict__ gidx) {
    __shared__ unsigned int  lval[512 * LVS];
    __shared__ unsigned char lidx[512 * LIS];
    const int PIXTILES = NPIX / 512;             // 36
    int tile  = blockIdx.x % PIXTILES;
    int chunk = blockIdx.x / PIXTILES;
    int t = threadIdx.x;
    int pix0 = tile * 512 + 2 * t;
    int b = pix0 / HWDIM;                        // pair never straddles b (even boundary)
    int p0 = pix0 - b * HWDIM;
    int s0 = chunk * CHUNK;
    const float2* ptr = (const float2*)(corr + ((size_t)b * HWDIM + s0) * HWDIM + p0);
    int c0 = 0, c1 = 0;
    const int r0 = 2 * t, r1 = 2 * t + 1;
    for (int batch = 0; batch < NBATCH; ++batch) {
        float2 r[BLEN];
#pragma unroll
        for (int u = 0; u < BLEN; ++u)
            r[u] = ptr[(size_t)(batch * BLEN + u) * (HWDIM / 2)];
#pragma unroll
        for (int u = 0; u < BLEN; ++u) {
            int j = batch * BLEN + u;
            int w0 = c0 < CAPC - 1 ? c0 : CAPC - 1;
            lval[r0 * LVS + w0] = fkey(r[u].x);
            lidx[r0 * LIS + w0] = (unsigned char)j;
            c0 += (r[u].x > TAU) ? 1 : 0;
            int w1 = c1 < CAPC - 1 ? c1 : CAPC - 1;
            lval[r1 * LVS + w1] = fkey(r[u].y);
            lidx[r1 * LIS + w1] = (unsigned char)j;
            c1 += (r[u].y > TAU) ? 1 : 0;
        }
    }
    // rows are thread-private: no barrier needed. Flush full 64B/16B records.
#pragma unroll
    for (int h = 0; h < 2; ++h) {
        int px = pix0 + h, row = 2 * t + h;
        uint4 q0, q1, q2, q3;
        q0.x = lval[row*LVS+ 0]; q0.y = lval[row*LVS+ 1]; q0.z = lval[row*LVS+ 2]; q0.w = lval[row*LVS+ 3];
        q1.x = lval[row*LVS+ 4]; q1.y = lval[row*LVS+ 5]; q1.z = lval[row*LVS+ 6]; q1.w = lval[row*LVS+ 7];
        q2.x = lval[row*LVS+ 8]; q2.y = lval[row*LVS+ 9]; q2.z = lval[row*LVS+10]; q2.w = lval[row*LVS+11];
        q3 = q2;                                          // slots 12..15 junk (gated by cnt)
        uint4* vr = (uint4*)(gval + (size_t)px * (NCHUNK * REC) + chunk * REC);
        vr[0] = q0; vr[1] = q1; vr[2] = q2; vr[3] = q3;
        unsigned int i0 = *(const unsigned int*)&lidx[row * LIS + 0];
        unsigned int i1 = *(const unsigned int*)&lidx[row * LIS + 4];
        unsigned int i2 = *(const unsigned int*)&lidx[row * LIS + 8];
        uint4 qi; qi.x = i0; qi.y = i1; qi.z = i2; qi.w = i2;
        *(uint4*)(gidx + (size_t)px * (NCHUNK * REC) + chunk * REC) = qi;
        cntc[(size_t)chunk * NPIX + px] = (unsigned char)(h ? c1 : c0);
    }
}

// bitonic compare-exchange across lanes (elements: A=i.e. lane, B=lane+64)
#define STAGE_SHFL(k, j) {                                                    \
    unsigned long long pA = __shfl_xor(A, (j), 64);                           \
    unsigned long long pB = __shfl_xor(B, (j), 64);                           \
    bool up = ((lane & (j)) == 0);                                            \
    bool dA = ((lane & (k)) == 0);                                            \
    bool dB = (((lane + 64) & (k)) == 0);                                     \
    bool gA = (A > pA), gB = (B > pB);                                        \
    A = ((up == dA) == gA) ? A : pA;                                          \
    B = ((up == dB) == gB) ? B : pB; }

// ---------------- K2: one WAVE per pixel — compact + bitonic-128 + gather ----------------
__global__ __launch_bounds__(256) void k2_select(const float* __restrict__ corr,
                                                 const float* __restrict__ lblT,
                                                 const unsigned char* __restrict__ cntc,
                                                 const unsigned int* __restrict__ gval,
                                                 const unsigned char* __restrict__ gidx,
                                                 float* __restrict__ out) {
    __shared__ unsigned long long kbuf[4][128];
    __shared__ unsigned int cbuf[4][32];
    __shared__ unsigned int pbuf[4][32];
    __shared__ float        svb[4][TOPK];
    __shared__ unsigned int ssb[4][TOPK];
    int wid = threadIdx.x >> 6, lane = threadIdx.x & 63;
    int pix = blockIdx.x * 4 + wid;
    int b = pix / HWDIM, p = pix - b * HWDIM;

    unsigned int c = (lane < 32) ? (unsigned int)cntc[(size_t)lane * NPIX + pix] : 0u;
    bool bad = (lane < 32) && (c >= CAPC);            // slot-11 untrusted at cnt>=12
    unsigned long long badm = __ballot(bad);
    unsigned int pf = c;
#pragma unroll
    for (int d2 = 1; d2 < 32; d2 <<= 1) {
        unsigned int o = __shfl_up(pf, d2, 64);
        if (lane >= d2) pf += o;
    }
    unsigned int total = __shfl(pf, 31, 64);
    if (lane < 32) { cbuf[wid][lane] = c; pbuf[wid][lane] = pf - c; }
    bool fb = (badm != 0ull) || (total < TOPK) || (total > 128);

    if (!fb) {
        kbuf[wid][lane] = 0ull; kbuf[wid][lane + 64] = 0ull;
        const unsigned int*  gv = gval + (size_t)pix * (NCHUNK * REC);
        const unsigned char* gi = gidx + (size_t)pix * (NCHUNK * REC);
        unsigned int vv[8]; unsigned char jj[8];
#pragma unroll
        for (int k = 0; k < 8; ++k) { vv[k] = gv[lane + 64 * k]; jj[k] = gi[lane + 64 * k]; }
#pragma unroll
        for (int k = 0; k < 8; ++k) {
            int e = lane + 64 * k, ch = e >> 4, sl = e & 15;
            unsigned int cn = cbuf[wid][ch];
            if ((unsigned int)sl < cn) {              // cn <= 11 on trusted path
                int tgt = (int)pbuf[wid][ch] + sl;    // < total <= 128
                kbuf[wid][tgt] = mk64(vv[k], (unsigned int)(ch * CHUNK + jj[k]));
            }
        }
        unsigned long long A = kbuf[wid][lane], B = kbuf[wid][lane + 64];
        // bitonic sort of 128 keys, descending (sentinel 0 sinks to the end)
        STAGE_SHFL(2, 1)
        STAGE_SHFL(4, 2)  STAGE_SHFL(4, 1)
        STAGE_SHFL(8, 4)  STAGE_SHFL(8, 2)  STAGE_SHFL(8, 1)
        STAGE_SHFL(16, 8) STAGE_SHFL(16, 4) STAGE_SHFL(16, 2) STAGE_SHFL(16, 1)
        STAGE_SHFL(32, 16) STAGE_SHFL(32, 8) STAGE_SHFL(32, 4) STAGE_SHFL(32, 2) STAGE_SHFL(32, 1)
        STAGE_SHFL(64, 32) STAGE_SHFL(64, 16) STAGE_SHFL(64, 8) STAGE_SHFL(64, 4) STAGE_SHFL(64, 2) STAGE_SHFL(64, 1)
        { unsigned long long mx = A > B ? A : B, mn = A > B ? B : A; A = mx; B = mn; }  // k=128, j=64
        STAGE_SHFL(128, 32) STAGE_SHFL(128, 16) STAGE_SHFL(128, 8)
        STAGE_SHFL(128, 4)  STAGE_SHFL(128, 2)  STAGE_SHFL(128, 1)
        if (lane < TOPK) {
            svb[wid][lane] = fkey_inv((unsigned int)(A >> 32));
            ssb[wid][lane] = 0xFFFFFFFFu - (unsigned int)A;
        }
    } else {
        // exact wave-parallel rescan: 36 rows/lane in regs, 20x extract-max
        const float* cp = corr + (size_t)b * HWDIM * HWDIM + p;
        unsigned int fk[36];
#pragma unroll
        for (int i = 0; i < 36; ++i) fk[i] = fkey(cp[(size_t)(i * 64 + lane) * HWDIM]);
        for (int it = 0; it < TOPK; ++it) {
            unsigned int m = 0;
#pragma unroll
            for (int i = 0; i < 36; ++i) m = m > fk[i] ? m : fk[i];
#pragma unroll
            for (int d2 = 1; d2 < 64; d2 <<= 1) { unsigned int o = __shfl_xor(m, d2, 64); m = m > o ? m : o; }
            int pos = -1;
#pragma unroll
            for (int i = 35; i >= 0; --i) if (fk[i] == m) pos = i;   // smallest local pos
            unsigned int smy = (pos >= 0) ? (unsigned int)(pos * 64 + lane) : 0xFFFFFFFFu;
#pragma unroll
            for (int d2 = 1; d2 < 64; d2 <<= 1) { unsigned int o = __shfl_xor(smy, d2, 64); smy = smy < o ? smy : o; }
            if (pos >= 0 && (unsigned int)(pos * 64 + lane) == smy) {
#pragma unroll
                for (int i = 0; i < 36; ++i) fk[i] = (i == pos) ? 0u : fk[i];  // static clear
            }
            if (lane == 0) { svb[wid][it] = fkey_inv(m); ssb[wid][it] = smy; }
        }
    }
    // common epilogue: lane<8 owns channel c
    if (lane < NCH) {
        float sv[TOPK]; unsigned int ss[TOPK];
#pragma unroll
        for (int i = 0; i < TOPK; ++i) { sv[i] = svb[wid][i]; ss[i] = ssb[wid][i]; }
        float acc = 0.f;
#pragma unroll
        for (int i = 0; i < TOPK; ++i)
            acc += sv[i] * lblT[((size_t)b * HWDIM + ss[i]) * NCH + lane];
        out[((size_t)b * NCH + lane) * HWDIM + p] = acc;
    }
}

// ---------------- fallback (ws too small): exact, self-contained ----------------
__global__ __launch_bounds__(64) void k_fallback(const float* __restrict__ corr,
                                                 const float* __restrict__ lbl,
                                                 float* __restrict__ out) {
    int pix = blockIdx.x * 64 + threadIdx.x;
    int b = pix / HWDIM, p = pix - b * HWDIM;
    unsigned long long d[TOPK];
#pragma unroll
    for (int i = 0; i < TOPK; ++i) d[i] = 0ull;
    const float* cp = corr + (size_t)b * HWDIM * HWDIM + p;
    for (int s = 0; s < HWDIM; ++s)
        PUSH(mk64(fkey(cp[(size_t)s * HWDIM]), (unsigned int)s));
    float acc[NCH];
#pragma unroll
    for (int c = 0; c < NCH; ++c) acc[c] = 0.0f;
    const float* lb = lbl + (size_t)b * NCH * HWDIM;
#pragma unroll
    for (int i = 0; i < TOPK; ++i) {
        float v = fkey_inv((unsigned int)(d[i] >> 32));
        unsigned int s = 0xFFFFFFFFu - (unsigned int)d[i];
#pragma unroll
        for (int c = 0; c < NCH; ++c) acc[c] += v * lb[(size_t)c * HWDIM + s];
    }
#pragma unroll
    for (int c = 0; c < NCH; ++c)
        out[((size_t)b * NCH + c) * HWDIM + p] = acc[c];
}

extern "C" void kernel_launch(void* const* d_in, const int* in_sizes, int n_in,
                              void* d_out, int out_size, void* d_ws, size_t ws_size,
                              hipStream_t stream) {
    const float* corr = (const float*)d_in[0];  // (8, 2304, 48, 48) fp32
    const float* lbl  = (const float*)d_in[1];  // (8, 8, 48, 48) fp32
    float* out = (float*)d_out;

    // ws layout (256B-aligned): [gval 37.7MB][gidx 9.4MB][cntc 0.6MB][lblT 0.6MB] ~= 48.4MB
    auto align256 = [](size_t x) { return (x + 255) & ~(size_t)255; };
    size_t off = 0;
    size_t gval_off = off; off += align256((size_t)NPIX * NCHUNK * REC * 4);
    size_t gidx_off = off; off += align256((size_t)NPIX * NCHUNK * REC);
    size_t cntc_off = off; off += align256((size_t)NCHUNK * NPIX);
    size_t lblT_off = off; off += align256((size_t)NPIX * NCH * 4);
    size_t needed = off;

    if (ws_size >= needed) {
        unsigned int* gval = (unsigned int*)((char*)d_ws + gval_off);
        unsigned char* gidx = (unsigned char*)((char*)d_ws + gidx_off);
        unsigned char* cntc = (unsigned char*)((char*)d_ws + cntc_off);
        float* lblT = (float*)((char*)d_ws + lblT_off);

        k0_transpose<<<dim3(NPIX / 256), dim3(256), 0, stream>>>(lbl, lblT);
        k1_filter<<<dim3((NPIX / 512) * NCHUNK), dim3(256), 0, stream>>>(corr, cntc, gval, gidx);
        k2_select<<<dim3(NPIX / 4), dim3(256), 0, stream>>>(corr, lblT, cntc, gval, gidx, out);
    } else {
        k_fallback<<<dim3(NPIX / 64), dim3(64), 0, stream>>>(corr, lbl, out);
    }
}